// Round 16
// baseline (208.351 us; speedup 1.0000x reference)
//
#include <hip/hip_runtime.h>
#include <hip/hip_bf16.h>
#include <hip/hip_cooperative_groups.h>

namespace cg = cooperative_groups;

// Problem constants (QREncoder: path signature depth 4 + linear head)
#define BATCH 64
#define LSEQ 256
#define CIN 7
#define CC 8           // channels incl. time
#define NSIG 4680      // 8 + 64 + 512 + 4096
#define KPAD 4736      // NSIG padded to multiple of 64
#define TSTEPS 255     // LSEQ - 1
#define ODIM 512
#define NCHUNK 16      // time chunks for sig write parallelism
#define CH 16          // steps per chunk (last chunk: 15)
#define NKT 74         // KPAD / 64 K-steps
#define BM 256
#define BN 128
#define M_TOTAL 16320  // BATCH * TSTEPS
#define WCVT_BLK 592   // ODIM*KPAD/8/512

typedef __attribute__((ext_vector_type(8))) unsigned short ushort8;
typedef __attribute__((ext_vector_type(8))) __bf16 bf16x8;
typedef __attribute__((ext_vector_type(4))) float f32x4;

__device__ __forceinline__ unsigned short f2bf(float x) {
    __hip_bfloat16 h = __float2bfloat16(x);   // RNE
    return *(unsigned short*)&h;
}

#define GLDS16(gp, lp)                                                      \
    __builtin_amdgcn_global_load_lds(                                       \
        (const __attribute__((address_space(1))) void*)(gp),                \
        (__attribute__((address_space(3))) void*)(lp), 16, 0, 0)

// ===========================================================================
// Fused cooperative kernel: 256 blocks x 512 threads, 1 block/CU.
// Phase A: ckpt scan (4 blocks/batch).   grid.sync
// Phase B: wcvt + sig_write chunk-units. grid.sync
// Phase C: R10-verified MFMA GEMM (74.7us standalone).
// All phase bodies verbatim from the R15-verified kernels (absmax 4.0).
// ===========================================================================
__global__ __launch_bounds__(512) void fused_kernel(const float* __restrict__ inp,
                                                    const float* __restrict__ W,
                                                    const float* __restrict__ bias,
                                                    float* __restrict__ out,
                                                    unsigned short* __restrict__ sig,
                                                    float* __restrict__ ckpt,
                                                    unsigned short* __restrict__ Wb) {
    __shared__ __align__(16) char ldsraw[147456];
    const int bx  = blockIdx.x;            // 0..255
    const int tid = threadIdx.x;
    cg::grid_group grid = cg::this_grid();

    // ---------------- Phase A: checkpoint scan (4 blocks/batch) -----------
    {
        float* sDx = (float*)ldsraw;
        const int b = bx >> 2, q = bx & 3;
        const float* ip = inp + (size_t)b * LSEQ * CIN;
        for (int i = tid; i < TSTEPS * CC; i += 512) {
            int t = i >> 3, c = i & 7;
            sDx[i] = (c == 0) ? (1.0f / 255.0f)
                              : ip[(t + 1) * CIN + (c - 1)] - ip[t * CIN + (c - 1)];
        }
        __syncthreads();

        const int o  = q * 128 + (tid >> 2);
        const int e2 = tid & 3;
        const int i1 = o >> 6, i2 = (o >> 3) & 7, i3 = o & 7;
        float a1 = 0.0f, a2 = 0.0f, a3 = 0.0f, a4a = 0.0f, a4b = 0.0f;

        for (int t = 0; t < 240; ++t) {
            const float* v = &sDx[t * CC];
            const float va = v[i1], vb = v[i2], vc = v[i3];
            const float vA = v[e2], vB = v[e2 + 4];
            const float e3s = va * vb * vc * (1.0f / 6.0f);
            const float T4 = e3s * 0.25f + a1 * vb * vc * (1.0f / 6.0f)
                           + a2 * vc * 0.5f + a3;
            a4a += vA * T4;
            a4b += vB * T4;
            a3 += e3s + (a1 * vb * 0.5f + a2) * vc;
            a2 += vb * (0.5f * va + a1);
            a1 += va;

            if (((t + 1) & 15) == 0) {
                const int c = ((t + 1) >> 4) - 1;   // 0..14
                float* cp = ckpt + ((size_t)b * 15 + c) * NSIG;
                cp[584 + o * 8 + e2]     = a4a;
                cp[584 + o * 8 + e2 + 4] = a4b;
                if (e2 == 0) {
                    cp[72 + o] = a3;
                    if ((o & 7) == 0)  cp[8 + (o >> 3)] = a2;
                    if ((o & 63) == 0) cp[i1] = a1;
                }
            }
        }
    }
    grid.sync();

    // ---------------- Phase B: W conversion + sig chunk-units -------------
    {
        for (int u = bx; u < WCVT_BLK; u += 256) {
            const int vid = u * 512 + tid;
            if (vid < ODIM * (KPAD / 8)) {
                const int n = vid / (KPAD / 8);
                const int g = vid - n * (KPAD / 8);
                ushort8 pk;
                if (g < NSIG / 8) {
                    const float* wp = W + (size_t)n * NSIG + g * 8;
                    float4 f0 = *(const float4*)wp;
                    float4 f1 = *(const float4*)(wp + 4);
                    pk[0] = f2bf(f0.x); pk[1] = f2bf(f0.y);
                    pk[2] = f2bf(f0.z); pk[3] = f2bf(f0.w);
                    pk[4] = f2bf(f1.x); pk[5] = f2bf(f1.y);
                    pk[6] = f2bf(f1.z); pk[7] = f2bf(f1.w);
                } else {
#pragma unroll
                    for (int e = 0; e < 8; ++e) pk[e] = 0;
                }
                *(ushort8*)(Wb + (size_t)n * KPAD + g * 8) = pk;
            }
        }

        float* sDx = (float*)ldsraw;
        for (int u = bx; u < NCHUNK * BATCH; u += 256) {
            const int chunk = u & 15;
            const int b     = u >> 4;
            const int t0    = chunk * CH;
            const int t1    = (chunk == NCHUNK - 1) ? TSTEPS : t0 + CH;

            __syncthreads();                      // sDx reuse across units
            const float* ip = inp + (size_t)b * LSEQ * CIN;
            for (int i = tid; i < (t1 - t0) * CC; i += 512) {
                int t = t0 + (i >> 3), c = i & 7;
                sDx[i] = (c == 0) ? (1.0f / 255.0f)
                                  : ip[(t + 1) * CIN + (c - 1)] - ip[t * CIN + (c - 1)];
            }
            __syncthreads();

            const int i1 = tid >> 6;
            const int i2 = (tid >> 3) & 7;
            const int i3 = tid & 7;

            float a1own, a2own, a3;
            float a4[8];
            if (chunk == 0) {
                a1own = a2own = a3 = 0.0f;
#pragma unroll
                for (int e = 0; e < 8; ++e) a4[e] = 0.0f;
            } else {
                const float* cp = ckpt + ((size_t)b * 15 + (chunk - 1)) * NSIG;
                a1own = cp[i1];
                a2own = cp[8 + (tid >> 3)];
                a3    = cp[72 + tid];
                float4 q0 = *(const float4*)&cp[584 + tid * 8];
                float4 q1 = *(const float4*)&cp[584 + tid * 8 + 4];
                a4[0] = q0.x; a4[1] = q0.y; a4[2] = q0.z; a4[3] = q0.w;
                a4[4] = q1.x; a4[5] = q1.y; a4[6] = q1.z; a4[7] = q1.w;
            }

            for (int t = t0; t < t1; ++t) {
                const float* v = &sDx[(t - t0) * CC];
                const float4 vlo = *(const float4*)&v[0];
                const float4 vhi = *(const float4*)&v[4];
                const float va = v[i1], vb = v[i2], vc = v[i3];
                const float e3s = va * vb * vc * (1.0f / 6.0f);
                const float T4 = e3s * 0.25f + a1own * vb * vc * (1.0f / 6.0f)
                               + a2own * vc * 0.5f + a3;
                a4[0] += vlo.x * T4; a4[1] += vlo.y * T4;
                a4[2] += vlo.z * T4; a4[3] += vlo.w * T4;
                a4[4] += vhi.x * T4; a4[5] += vhi.y * T4;
                a4[6] += vhi.z * T4; a4[7] += vhi.w * T4;
                a3 += e3s + (a1own * vb * 0.5f + a2own) * vc;
                a2own += vb * (0.5f * va + a1own);
                a1own += va;

                unsigned short* row = sig + ((size_t)b * TSTEPS + t) * KPAD;
                ushort8 pack;
#pragma unroll
                for (int e = 0; e < 8; ++e) pack[e] = f2bf(a4[e]);
                *(ushort8*)(row + 584 + tid * 8) = pack;                // L4
                row[72 + tid] = f2bf(a3);                               // L3
                if ((tid & 63) == 0) row[i1] = f2bf(a1own);             // L1
                if ((tid & 7) == 0) row[8 + (tid >> 3)] = f2bf(a2own);  // L2
                if (tid >= 448 && tid < 504) row[4232 + tid] = 0;       // pad
            }
        }
    }
    grid.sync();

    // ---------------- Phase C: MFMA GEMM (R10-verified schedule) ----------
    {
        unsigned short (*As)[BM * 64] = (unsigned short (*)[BM * 64])(ldsraw);
        unsigned short (*Bs)[BN * 64] =
            (unsigned short (*)[BN * 64])(ldsraw + 3 * BM * 64 * 2);

        const int li = bx;
        const int x  = li & 7;                 // XCD (round-robin assumption)
        const int j  = li >> 3;                // 0..31 within XCD
        const int mt = x * 8 + (j >> 2);       // 8 m-panels per XCD
        const int nt = j & 3;
        const int Mrows = M_TOTAL;

        const int lane = tid & 63;
        const int wv   = tid >> 6;
        const int wr   = wv >> 1;
        const int wc   = wv & 1;
        const int lr   = lane & 15;
        const int lq   = lane >> 4;
        const int sb   = lr & 7;

        const f32x4 z4 = {0.0f, 0.0f, 0.0f, 0.0f};
        f32x4 acc[4][4];
#pragma unroll
        for (int i = 0; i < 4; ++i)
#pragma unroll
            for (int j2 = 0; j2 < 4; ++j2) acc[i][j2] = z4;

        const int srow = tid >> 3;
        const int gcb  = (tid & 7) ^ (srow & 7);
        const int scol = gcb * 8;

        const unsigned short* aptr[4];
        const unsigned short* bptr[2];
#pragma unroll
        for (int i = 0; i < 4; ++i) {
            int gr = mt * BM + i * 64 + srow;
            if (gr >= Mrows) gr = 0;
            aptr[i] = sig + (size_t)gr * KPAD + scol;
        }
#pragma unroll
        for (int i = 0; i < 2; ++i)
            bptr[i] = Wb + (size_t)(nt * BN + i * 64 + srow) * KPAD + scol;

        const int kel0 = ((lq)     ^ sb) * 8;
        const int kel1 = ((4 + lq) ^ sb) * 8;
        const int aoff = (wr * 64 + lr) * 64;
        const int boff = (wc * 64 + lr) * 64;

#define STAGE_ALL(buf, koff)                                                \
    do {                                                                    \
        _Pragma("unroll")                                                   \
        for (int i_ = 0; i_ < 4; ++i_)                                      \
            GLDS16(aptr[i_] + (koff),                                       \
                   ((char*)As[buf]) + i_ * 8192 + tid * 16);                \
        _Pragma("unroll")                                                   \
        for (int i_ = 0; i_ < 2; ++i_)                                      \
            GLDS16(bptr[i_] + (koff),                                       \
                   ((char*)Bs[buf]) + i_ * 8192 + tid * 16);                \
    } while (0)

        STAGE_ALL(0, 0);
        STAGE_ALL(1, 64);
        asm volatile("s_waitcnt vmcnt(6)" ::: "memory");
        __builtin_amdgcn_sched_barrier(0);
        __builtin_amdgcn_s_barrier();
        __builtin_amdgcn_sched_barrier(0);

        bf16x8 afP[4], bfP[4], afN[4], bfN[4];
        {
            const unsigned short* as0 = &As[0][0];
            const unsigned short* bs0 = &Bs[0][0];
#pragma unroll
            for (int i = 0; i < 4; ++i)
                afP[i] = *(const bf16x8*)&as0[aoff + i * 1024 + kel0];
#pragma unroll
            for (int j2 = 0; j2 < 4; ++j2)
                bfP[j2] = *(const bf16x8*)&bs0[boff + j2 * 1024 + kel0];
        }
        __builtin_amdgcn_sched_barrier(0);

        int cur = 0, nxt = 1, nn = 2;
        for (int t = 0; t < NKT; ++t) {
            const unsigned short* as = &As[0][0] + cur * (BM * 64);
            const unsigned short* bs = &Bs[0][0] + cur * (BN * 64);

#pragma unroll
            for (int i = 0; i < 4; ++i)
                afN[i] = *(const bf16x8*)&as[aoff + i * 1024 + kel1];
#pragma unroll
            for (int j2 = 0; j2 < 4; ++j2)
                bfN[j2] = *(const bf16x8*)&bs[boff + j2 * 1024 + kel1];
            if (t + 2 < NKT) STAGE_ALL(nn, (t + 2) * 64);
            __builtin_amdgcn_sched_barrier(0);

            asm volatile("s_waitcnt lgkmcnt(8)" ::: "memory");
            __builtin_amdgcn_sched_barrier(0);
            __builtin_amdgcn_s_setprio(1);
#pragma unroll
            for (int i = 0; i < 4; ++i)
#pragma unroll
                for (int j2 = 0; j2 < 4; ++j2)
                    acc[i][j2] = __builtin_amdgcn_mfma_f32_16x16x32_bf16(
                        afP[i], bfP[j2], acc[i][j2], 0, 0, 0);
            __builtin_amdgcn_s_setprio(0);
            __builtin_amdgcn_sched_barrier(0);

            asm volatile("s_waitcnt lgkmcnt(0)" ::: "memory");
            __builtin_amdgcn_sched_barrier(0);
            if (t + 1 < NKT) {
                if (t + 2 < NKT) {
                    asm volatile("s_waitcnt vmcnt(6)" ::: "memory");
                } else {
                    asm volatile("s_waitcnt vmcnt(0)" ::: "memory");
                }
                __builtin_amdgcn_sched_barrier(0);
                __builtin_amdgcn_s_barrier();
                __builtin_amdgcn_sched_barrier(0);
                const unsigned short* asn = &As[0][0] + nxt * (BM * 64);
                const unsigned short* bsn = &Bs[0][0] + nxt * (BN * 64);
#pragma unroll
                for (int i = 0; i < 4; ++i)
                    afP[i] = *(const bf16x8*)&asn[aoff + i * 1024 + kel0];
#pragma unroll
                for (int j2 = 0; j2 < 4; ++j2)
                    bfP[j2] = *(const bf16x8*)&bsn[boff + j2 * 1024 + kel0];
                __builtin_amdgcn_sched_barrier(0);
            }

            __builtin_amdgcn_s_setprio(1);
#pragma unroll
            for (int i = 0; i < 4; ++i)
#pragma unroll
                for (int j2 = 0; j2 < 4; ++j2)
                    acc[i][j2] = __builtin_amdgcn_mfma_f32_16x16x32_bf16(
                        afN[i], bfN[j2], acc[i][j2], 0, 0, 0);
            __builtin_amdgcn_s_setprio(0);
            __builtin_amdgcn_sched_barrier(0);

            const int tmp = cur; cur = nxt; nxt = nn; nn = tmp;
        }

        float bn[4];
#pragma unroll
        for (int j2 = 0; j2 < 4; ++j2)
            bn[j2] = bias[nt * BN + wc * 64 + j2 * 16 + lr];

#pragma unroll
        for (int i = 0; i < 4; ++i) {
            const int mbase = mt * BM + wr * 64 + i * 16 + lq * 4;
#pragma unroll
            for (int r = 0; r < 4; ++r) {
                const int m = mbase + r;
                if (m < Mrows) {
#pragma unroll
                    for (int j2 = 0; j2 < 4; ++j2) {
                        const int n = nt * BN + wc * 64 + j2 * 16 + lr;
                        out[(size_t)m * ODIM + n] = acc[i][j2][r] + bn[j2];
                    }
                }
            }
        }
#undef STAGE_ALL
    }
}

// ===========================================================================
// Fallback 3-kernel path (verbatim R15) for when ws can't hold all batches.
// ===========================================================================
__global__ __launch_bounds__(512) void prep_kernel(const float* __restrict__ inp,
                                                   float* __restrict__ ckpt,
                                                   const float* __restrict__ W,
                                                   unsigned short* __restrict__ Wb,
                                                   int nb) {
    __shared__ float sDx[TSTEPS * CC];
    const int bx  = blockIdx.x;
    const int tid = threadIdx.x;

    if (bx < 4 * nb) {
        const int b = bx >> 2, q = bx & 3;
        const float* ip = inp + (size_t)b * LSEQ * CIN;
        for (int i = tid; i < TSTEPS * CC; i += 512) {
            int t = i >> 3, c = i & 7;
            sDx[i] = (c == 0) ? (1.0f / 255.0f)
                              : ip[(t + 1) * CIN + (c - 1)] - ip[t * CIN + (c - 1)];
        }
        __syncthreads();

        const int o  = q * 128 + (tid >> 2);
        const int e2 = tid & 3;
        const int i1 = o >> 6, i2 = (o >> 3) & 7, i3 = o & 7;
        float a1 = 0.0f, a2 = 0.0f, a3 = 0.0f, a4a = 0.0f, a4b = 0.0f;

        for (int t = 0; t < 240; ++t) {
            const float* v = &sDx[t * CC];
            const float va = v[i1], vb = v[i2], vc = v[i3];
            const float vA = v[e2], vB = v[e2 + 4];
            const float e3s = va * vb * vc * (1.0f / 6.0f);
            const float T4 = e3s * 0.25f + a1 * vb * vc * (1.0f / 6.0f)
                           + a2 * vc * 0.5f + a3;
            a4a += vA * T4;
            a4b += vB * T4;
            a3 += e3s + (a1 * vb * 0.5f + a2) * vc;
            a2 += vb * (0.5f * va + a1);
            a1 += va;

            if (((t + 1) & 15) == 0) {
                const int c = ((t + 1) >> 4) - 1;
                float* cp = ckpt + ((size_t)b * 15 + c) * NSIG;
                cp[584 + o * 8 + e2]     = a4a;
                cp[584 + o * 8 + e2 + 4] = a4b;
                if (e2 == 0) {
                    cp[72 + o] = a3;
                    if ((o & 7) == 0)  cp[8 + (o >> 3)] = a2;
                    if ((o & 63) == 0) cp[i1] = a1;
                }
            }
        }
    } else {
        const int vid = (bx - 4 * nb) * 512 + tid;
        if (vid < ODIM * (KPAD / 8)) {
            const int n = vid / (KPAD / 8);
            const int g = vid - n * (KPAD / 8);
            ushort8 pk;
            if (g < NSIG / 8) {
                const float* wp = W + (size_t)n * NSIG + g * 8;
                float4 f0 = *(const float4*)wp;
                float4 f1 = *(const float4*)(wp + 4);
                pk[0] = f2bf(f0.x); pk[1] = f2bf(f0.y);
                pk[2] = f2bf(f0.z); pk[3] = f2bf(f0.w);
                pk[4] = f2bf(f1.x); pk[5] = f2bf(f1.y);
                pk[6] = f2bf(f1.z); pk[7] = f2bf(f1.w);
            } else {
#pragma unroll
                for (int e = 0; e < 8; ++e) pk[e] = 0;
            }
            *(ushort8*)(Wb + (size_t)n * KPAD + g * 8) = pk;
        }
    }
}

__global__ __launch_bounds__(512) void sig_write_kernel(const float* __restrict__ inp,
                                                        const float* __restrict__ ckpt,
                                                        unsigned short* __restrict__ sig) {
    __shared__ float sDx[CH * CC];

    const int chunk = blockIdx.x;
    const int b     = blockIdx.y;
    const int tid   = threadIdx.x;
    const int t0    = chunk * CH;
    const int t1    = (chunk == NCHUNK - 1) ? TSTEPS : t0 + CH;

    const float* ip = inp + (size_t)b * LSEQ * CIN;
    for (int i = tid; i < (t1 - t0) * CC; i += 512) {
        int t = t0 + (i >> 3), c = i & 7;
        sDx[i] = (c == 0) ? (1.0f / 255.0f)
                          : ip[(t + 1) * CIN + (c - 1)] - ip[t * CIN + (c - 1)];
    }
    __syncthreads();

    const int i1 = tid >> 6;
    const int i2 = (tid >> 3) & 7;
    const int i3 = tid & 7;

    float a1own, a2own, a3;
    float a4[8];
    if (chunk == 0) {
        a1own = a2own = a3 = 0.0f;
#pragma unroll
        for (int e = 0; e < 8; ++e) a4[e] = 0.0f;
    } else {
        const float* cp = ckpt + ((size_t)b * 15 + (chunk - 1)) * NSIG;
        a1own = cp[i1];
        a2own = cp[8 + (tid >> 3)];
        a3    = cp[72 + tid];
        float4 q0 = *(const float4*)&cp[584 + tid * 8];
        float4 q1 = *(const float4*)&cp[584 + tid * 8 + 4];
        a4[0] = q0.x; a4[1] = q0.y; a4[2] = q0.z; a4[3] = q0.w;
        a4[4] = q1.x; a4[5] = q1.y; a4[6] = q1.z; a4[7] = q1.w;
    }

    for (int t = t0; t < t1; ++t) {
        const float* v = &sDx[(t - t0) * CC];
        const float4 vlo = *(const float4*)&v[0];
        const float4 vhi = *(const float4*)&v[4];
        const float va = v[i1], vb = v[i2], vc = v[i3];
        const float e3s = va * vb * vc * (1.0f / 6.0f);
        const float T4 = e3s * 0.25f + a1own * vb * vc * (1.0f / 6.0f)
                       + a2own * vc * 0.5f + a3;
        a4[0] += vlo.x * T4; a4[1] += vlo.y * T4;
        a4[2] += vlo.z * T4; a4[3] += vlo.w * T4;
        a4[4] += vhi.x * T4; a4[5] += vhi.y * T4;
        a4[6] += vhi.z * T4; a4[7] += vhi.w * T4;
        a3 += e3s + (a1own * vb * 0.5f + a2own) * vc;
        a2own += vb * (0.5f * va + a1own);
        a1own += va;

        unsigned short* row = sig + ((size_t)b * TSTEPS + t) * KPAD;
        ushort8 pack;
#pragma unroll
        for (int e = 0; e < 8; ++e) pack[e] = f2bf(a4[e]);
        *(ushort8*)(row + 584 + tid * 8) = pack;
        row[72 + tid] = f2bf(a3);
        if ((tid & 63) == 0) row[i1] = f2bf(a1own);
        if ((tid & 7) == 0) row[8 + (tid >> 3)] = f2bf(a2own);
        if (tid >= 448 && tid < 504) row[4232 + tid] = 0;
    }
}

__global__ __launch_bounds__(512) void gemm_kernel(const unsigned short* __restrict__ A,
                                                   const unsigned short* __restrict__ Wb,
                                                   const float* __restrict__ bias,
                                                   float* __restrict__ out,
                                                   int Mrows) {
    __shared__ unsigned short As[3][BM * 64];
    __shared__ unsigned short Bs[3][BN * 64];

    const int tid = threadIdx.x;
    int nt, mt;
    if (gridDim.y == 64) {
        const int li = blockIdx.y * 4 + blockIdx.x;
        const int x  = li & 7;
        const int j  = li >> 3;
        mt = x * 8 + (j >> 2);
        nt = j & 3;
    } else {
        nt = blockIdx.x; mt = blockIdx.y;
    }
    const int lane = tid & 63;
    const int wv   = tid >> 6;
    const int wr   = wv >> 1;
    const int wc   = wv & 1;
    const int lr   = lane & 15;
    const int lq   = lane >> 4;
    const int sb   = lr & 7;

    const f32x4 z4 = {0.0f, 0.0f, 0.0f, 0.0f};
    f32x4 acc[4][4];
#pragma unroll
    for (int i = 0; i < 4; ++i)
#pragma unroll
        for (int j = 0; j < 4; ++j) acc[i][j] = z4;

    const int srow = tid >> 3;
    const int gcb  = (tid & 7) ^ (srow & 7);
    const int scol = gcb * 8;

    const unsigned short* aptr[4];
    const unsigned short* bptr[2];
#pragma unroll
    for (int i = 0; i < 4; ++i) {
        int gr = mt * BM + i * 64 + srow;
        if (gr >= Mrows) gr = 0;
        aptr[i] = A + (size_t)gr * KPAD + scol;
    }
#pragma unroll
    for (int i = 0; i < 2; ++i)
        bptr[i] = Wb + (size_t)(nt * BN + i * 64 + srow) * KPAD + scol;

    const int kel0 = ((lq)     ^ sb) * 8;
    const int kel1 = ((4 + lq) ^ sb) * 8;
    const int aoff = (wr * 64 + lr) * 64;
    const int boff = (wc * 64 + lr) * 64;

#define STAGE_ALL(buf, koff)                                                \
    do {                                                                    \
        _Pragma("unroll")                                                   \
        for (int i_ = 0; i_ < 4; ++i_)                                      \
            GLDS16(aptr[i_] + (koff),                                       \
                   ((char*)As[buf]) + i_ * 8192 + tid * 16);                \
        _Pragma("unroll")                                                   \
        for (int i_ = 0; i_ < 2; ++i_)                                      \
            GLDS16(bptr[i_] + (koff),                                       \
                   ((char*)Bs[buf]) + i_ * 8192 + tid * 16);                \
    } while (0)

    STAGE_ALL(0, 0);
    STAGE_ALL(1, 64);
    asm volatile("s_waitcnt vmcnt(6)" ::: "memory");
    __builtin_amdgcn_sched_barrier(0);
    __builtin_amdgcn_s_barrier();
    __builtin_amdgcn_sched_barrier(0);

    bf16x8 afP[4], bfP[4], afN[4], bfN[4];
    {
        const unsigned short* as0 = &As[0][0];
        const unsigned short* bs0 = &Bs[0][0];
#pragma unroll
        for (int i = 0; i < 4; ++i)
            afP[i] = *(const bf16x8*)&as0[aoff + i * 1024 + kel0];
#pragma unroll
        for (int j = 0; j < 4; ++j)
            bfP[j] = *(const bf16x8*)&bs0[boff + j * 1024 + kel0];
    }
    __builtin_amdgcn_sched_barrier(0);

    int cur = 0, nxt = 1, nn = 2;
    for (int t = 0; t < NKT; ++t) {
        const unsigned short* as = &As[0][0] + cur * (BM * 64);
        const unsigned short* bs = &Bs[0][0] + cur * (BN * 64);

#pragma unroll
        for (int i = 0; i < 4; ++i)
            afN[i] = *(const bf16x8*)&as[aoff + i * 1024 + kel1];
#pragma unroll
        for (int j = 0; j < 4; ++j)
            bfN[j] = *(const bf16x8*)&bs[boff + j * 1024 + kel1];
        if (t + 2 < NKT) STAGE_ALL(nn, (t + 2) * 64);
        __builtin_amdgcn_sched_barrier(0);

        asm volatile("s_waitcnt lgkmcnt(8)" ::: "memory");
        __builtin_amdgcn_sched_barrier(0);
        __builtin_amdgcn_s_setprio(1);
#pragma unroll
        for (int i = 0; i < 4; ++i)
#pragma unroll
            for (int j = 0; j < 4; ++j)
                acc[i][j] = __builtin_amdgcn_mfma_f32_16x16x32_bf16(
                    afP[i], bfP[j], acc[i][j], 0, 0, 0);
        __builtin_amdgcn_s_setprio(0);
        __builtin_amdgcn_sched_barrier(0);

        asm volatile("s_waitcnt lgkmcnt(0)" ::: "memory");
        __builtin_amdgcn_sched_barrier(0);
        if (t + 1 < NKT) {
            if (t + 2 < NKT) {
                asm volatile("s_waitcnt vmcnt(6)" ::: "memory");
            } else {
                asm volatile("s_waitcnt vmcnt(0)" ::: "memory");
            }
            __builtin_amdgcn_sched_barrier(0);
            __builtin_amdgcn_s_barrier();
            __builtin_amdgcn_sched_barrier(0);
            const unsigned short* asn = &As[0][0] + nxt * (BM * 64);
            const unsigned short* bsn = &Bs[0][0] + nxt * (BN * 64);
#pragma unroll
            for (int i = 0; i < 4; ++i)
                afP[i] = *(const bf16x8*)&asn[aoff + i * 1024 + kel0];
#pragma unroll
            for (int j = 0; j < 4; ++j)
                bfP[j] = *(const bf16x8*)&bsn[boff + j * 1024 + kel0];
            __builtin_amdgcn_sched_barrier(0);
        }

        __builtin_amdgcn_s_setprio(1);
#pragma unroll
        for (int i = 0; i < 4; ++i)
#pragma unroll
            for (int j = 0; j < 4; ++j)
                acc[i][j] = __builtin_amdgcn_mfma_f32_16x16x32_bf16(
                    afN[i], bfN[j], acc[i][j], 0, 0, 0);
        __builtin_amdgcn_s_setprio(0);
        __builtin_amdgcn_sched_barrier(0);

        const int tmp = cur; cur = nxt; nxt = nn; nn = tmp;
    }

    float bn[4];
#pragma unroll
    for (int j = 0; j < 4; ++j)
        bn[j] = bias[nt * BN + wc * 64 + j * 16 + lr];

#pragma unroll
    for (int i = 0; i < 4; ++i) {
        const int mbase = mt * BM + wr * 64 + i * 16 + lq * 4;
#pragma unroll
        for (int r = 0; r < 4; ++r) {
            const int m = mbase + r;
            if (m < Mrows) {
#pragma unroll
                for (int j = 0; j < 4; ++j) {
                    const int n = nt * BN + wc * 64 + j * 16 + lr;
                    out[(size_t)m * ODIM + n] = acc[i][j][r] + bn[j];
                }
            }
        }
    }
#undef STAGE_ALL
}

extern "C" void kernel_launch(void* const* d_in, const int* in_sizes, int n_in,
                              void* d_out, int out_size, void* d_ws, size_t ws_size,
                              hipStream_t stream) {
    const float* inp  = (const float*)d_in[0];
    const float* W    = (const float*)d_in[1];
    const float* bias = (const float*)d_in[2];
    float* out = (float*)d_out;

    const size_t wbBytes = (size_t)ODIM * KPAD * sizeof(unsigned short);
    const size_t sigPB   = (size_t)TSTEPS * KPAD * sizeof(unsigned short);
    const size_t ckptPB  = (size_t)15 * NSIG * sizeof(float);
    const size_t perB    = sigPB + ckptPB;

    int nbMax = (int)((ws_size - wbBytes) / perB);
    if (nbMax > BATCH) nbMax = BATCH;
    if (nbMax < 1) nbMax = 1;

    unsigned short* sig  = (unsigned short*)d_ws;
    float*          ckpt = (float*)((char*)d_ws + (size_t)nbMax * sigPB);
    unsigned short* Wb   = (unsigned short*)((char*)d_ws + (ws_size - wbBytes));

    if (nbMax >= BATCH) {
        // single cooperative launch: all phases fused, grid gaps eliminated
        const float* a0 = inp;
        const float* a1 = W;
        const float* a2 = bias;
        float* a3 = out;
        unsigned short* a4 = sig;
        float* a5 = ckpt;
        unsigned short* a6 = Wb;
        void* kargs[7] = {&a0, &a1, &a2, &a3, &a4, &a5, &a6};
        hipLaunchCooperativeKernel((void*)fused_kernel, dim3(256), dim3(512),
                                   kargs, 0, stream);
    } else {
        for (int b0 = 0; b0 < BATCH; b0 += nbMax) {
            const int nb = (b0 + nbMax <= BATCH) ? nbMax : (BATCH - b0);
            const int Mrows = nb * TSTEPS;
            const float* ipb = inp + (size_t)b0 * LSEQ * CIN;
            prep_kernel<<<4 * nb + WCVT_BLK, 512, 0, stream>>>(ipb, ckpt, W, Wb, nb);
            sig_write_kernel<<<dim3(NCHUNK, nb), 512, 0, stream>>>(ipb, ckpt, sig);
            gemm_kernel<<<dim3(ODIM / BN, (Mrows + BM - 1) / BM), 512, 0, stream>>>(
                sig, Wb, bias, out + (size_t)b0 * TSTEPS * ODIM, Mrows);
        }
    }
}

// Round 17
// 145.697 us; speedup vs baseline: 1.4300x; 1.4300x over previous
//
#include <hip/hip_runtime.h>
#include <hip/hip_bf16.h>

// Problem constants (QREncoder: path signature depth 4 + linear head)
#define BATCH 64
#define LSEQ 256
#define CIN 7
#define CC 8           // channels incl. time
#define NSIG 4680      // 8 + 64 + 512 + 4096
#define KPAD 4736      // NSIG padded to multiple of 64
#define TSTEPS 255     // LSEQ - 1
#define ODIM 512
#define NCHUNK 16      // time chunks for sig write parallelism
#define CH 16          // steps per chunk (last chunk: 15)
#define NKT 74         // KPAD / 64 K-steps
#define BM 256
#define BN 128
#define WCVT_BLK 592   // ODIM*KPAD/8/512

typedef __attribute__((ext_vector_type(8))) unsigned short ushort8;
typedef __attribute__((ext_vector_type(8))) __bf16 bf16x8;
typedef __attribute__((ext_vector_type(4))) float f32x4;

__device__ __forceinline__ unsigned short f2bf(float x) {
    __hip_bfloat16 h = __float2bfloat16(x);   // RNE
    return *(unsigned short*)&h;
}

#define GLDS16(gp, lp)                                                      \
    __builtin_amdgcn_global_load_lds(                                       \
        (const __attribute__((address_space(1))) void*)(gp),                \
        (__attribute__((address_space(3))) void*)(lp), 16, 0, 0)

// ---------------------------------------------------------------------------
// prep kernel (R11/R15-verified): scan-checkpoint part (4 blocks/batch) + W
// conversion part (vectorized float4x2 -> ushort8) riding the same launch.
// ---------------------------------------------------------------------------
__global__ __launch_bounds__(512) void prep_kernel(const float* __restrict__ inp,
                                                   float* __restrict__ ckpt,
                                                   const float* __restrict__ W,
                                                   unsigned short* __restrict__ Wb,
                                                   int nb) {
    __shared__ float sDx[TSTEPS * CC];
    const int bx  = blockIdx.x;
    const int tid = threadIdx.x;

    if (bx < 4 * nb) {
        const int b = bx >> 2, q = bx & 3;
        const float* ip = inp + (size_t)b * LSEQ * CIN;
        for (int i = tid; i < TSTEPS * CC; i += 512) {
            int t = i >> 3, c = i & 7;
            sDx[i] = (c == 0) ? (1.0f / 255.0f)
                              : ip[(t + 1) * CIN + (c - 1)] - ip[t * CIN + (c - 1)];
        }
        __syncthreads();

        const int o  = q * 128 + (tid >> 2);
        const int e2 = tid & 3;
        const int i1 = o >> 6, i2 = (o >> 3) & 7, i3 = o & 7;
        float a1 = 0.0f, a2 = 0.0f, a3 = 0.0f, a4a = 0.0f, a4b = 0.0f;

        for (int t = 0; t < 240; ++t) {
            const float* v = &sDx[t * CC];
            const float va = v[i1], vb = v[i2], vc = v[i3];
            const float vA = v[e2], vB = v[e2 + 4];
            const float e3s = va * vb * vc * (1.0f / 6.0f);
            const float T4 = e3s * 0.25f + a1 * vb * vc * (1.0f / 6.0f)
                           + a2 * vc * 0.5f + a3;
            a4a += vA * T4;
            a4b += vB * T4;
            a3 += e3s + (a1 * vb * 0.5f + a2) * vc;
            a2 += vb * (0.5f * va + a1);
            a1 += va;

            if (((t + 1) & 15) == 0) {
                const int c = ((t + 1) >> 4) - 1;   // 0..14
                float* cp = ckpt + ((size_t)b * 15 + c) * NSIG;
                cp[584 + o * 8 + e2]     = a4a;
                cp[584 + o * 8 + e2 + 4] = a4b;
                if (e2 == 0) {
                    cp[72 + o] = a3;
                    if ((o & 7) == 0)  cp[8 + (o >> 3)] = a2;
                    if ((o & 63) == 0) cp[i1] = a1;
                }
            }
        }
    } else {
        const int vid = (bx - 4 * nb) * 512 + tid;
        if (vid < ODIM * (KPAD / 8)) {
            const int n = vid / (KPAD / 8);
            const int g = vid - n * (KPAD / 8);
            ushort8 pk;
            if (g < NSIG / 8) {
                const float* wp = W + (size_t)n * NSIG + g * 8;
                float4 f0 = *(const float4*)wp;
                float4 f1 = *(const float4*)(wp + 4);
                pk[0] = f2bf(f0.x); pk[1] = f2bf(f0.y);
                pk[2] = f2bf(f0.z); pk[3] = f2bf(f0.w);
                pk[4] = f2bf(f1.x); pk[5] = f2bf(f1.y);
                pk[6] = f2bf(f1.z); pk[7] = f2bf(f1.w);
            } else {
#pragma unroll
                for (int e = 0; e < 8; ++e) pk[e] = 0;
            }
            *(ushort8*)(Wb + (size_t)n * KPAD + g * 8) = pk;
        }
    }
}

// ---------------------------------------------------------------------------
// Scan pass B (verified): grid (NCHUNK, nb). Block (chunk,b) loads the
// chunk's start state from ckpt, runs <=16 steps, writes sig rows (bf16).
// ---------------------------------------------------------------------------
__global__ __launch_bounds__(512) void sig_write_kernel(const float* __restrict__ inp,
                                                        const float* __restrict__ ckpt,
                                                        unsigned short* __restrict__ sig) {
    __shared__ float sDx[CH * CC];

    const int chunk = blockIdx.x;
    const int b     = blockIdx.y;
    const int tid   = threadIdx.x;
    const int t0    = chunk * CH;
    const int t1    = (chunk == NCHUNK - 1) ? TSTEPS : t0 + CH;

    const float* ip = inp + (size_t)b * LSEQ * CIN;
    for (int i = tid; i < (t1 - t0) * CC; i += 512) {
        int t = t0 + (i >> 3), c = i & 7;
        sDx[i] = (c == 0) ? (1.0f / 255.0f)
                          : ip[(t + 1) * CIN + (c - 1)] - ip[t * CIN + (c - 1)];
    }
    __syncthreads();

    const int i1 = tid >> 6;
    const int i2 = (tid >> 3) & 7;
    const int i3 = tid & 7;

    float a1own, a2own, a3;
    float a4[8];
    if (chunk == 0) {
        a1own = a2own = a3 = 0.0f;
#pragma unroll
        for (int e = 0; e < 8; ++e) a4[e] = 0.0f;
    } else {
        const float* cp = ckpt + ((size_t)b * 15 + (chunk - 1)) * NSIG;
        a1own = cp[i1];
        a2own = cp[8 + (tid >> 3)];
        a3    = cp[72 + tid];
        float4 q0 = *(const float4*)&cp[584 + tid * 8];
        float4 q1 = *(const float4*)&cp[584 + tid * 8 + 4];
        a4[0] = q0.x; a4[1] = q0.y; a4[2] = q0.z; a4[3] = q0.w;
        a4[4] = q1.x; a4[5] = q1.y; a4[6] = q1.z; a4[7] = q1.w;
    }

    for (int t = t0; t < t1; ++t) {
        const float* v = &sDx[(t - t0) * CC];
        const float4 vlo = *(const float4*)&v[0];
        const float4 vhi = *(const float4*)&v[4];
        const float va = v[i1], vb = v[i2], vc = v[i3];
        const float e3s = va * vb * vc * (1.0f / 6.0f);
        const float T4 = e3s * 0.25f + a1own * vb * vc * (1.0f / 6.0f)
                       + a2own * vc * 0.5f + a3;
        a4[0] += vlo.x * T4; a4[1] += vlo.y * T4;
        a4[2] += vlo.z * T4; a4[3] += vlo.w * T4;
        a4[4] += vhi.x * T4; a4[5] += vhi.y * T4;
        a4[6] += vhi.z * T4; a4[7] += vhi.w * T4;
        a3 += e3s + (a1own * vb * 0.5f + a2own) * vc;
        a2own += vb * (0.5f * va + a1own);
        a1own += va;

        unsigned short* row = sig + ((size_t)b * TSTEPS + t) * KPAD;
        ushort8 pack;
#pragma unroll
        for (int e = 0; e < 8; ++e) pack[e] = f2bf(a4[e]);
        *(ushort8*)(row + 584 + tid * 8) = pack;                // level 4
        row[72 + tid] = f2bf(a3);                               // level 3
        if ((tid & 63) == 0) row[i1] = f2bf(a1own);             // level 1
        if ((tid & 7) == 0) row[8 + (tid >> 3)] = f2bf(a2own);  // level 2
        if (tid >= 448 && tid < 504) row[4232 + tid] = 0;       // pad
    }
}

// ---------------------------------------------------------------------------
// MFMA GEMM (R10/R15-verified best: 74.7us, MfmaUtil 44%, conflicts 0).
// BM=256 x BN=128, BK=64, 8 waves (4Mx2N, each 64x64), 3 LDS buffers.
// Cross-tile pipeline: every ds_read burst streams under an MFMA cluster;
// ONE barrier per K-tile placed BETWEEN the two MFMA clusters; counted
// vmcnt(6) keeps tile t+2's loads in flight across the barrier.
// T2 XOR-swizzle (linear LDS dest + pre-swizzled global src + matching XOR
// on ds_read), XCD-grouped block swizzle, T5 setprio around MFMA clusters.
// ---------------------------------------------------------------------------
__global__ __launch_bounds__(512) void gemm_kernel(const unsigned short* __restrict__ A,
                                                   const unsigned short* __restrict__ Wb,
                                                   const float* __restrict__ bias,
                                                   float* __restrict__ out,
                                                   int Mrows) {
    __shared__ unsigned short As[3][BM * 64];   // 3 x 32 KB
    __shared__ unsigned short Bs[3][BN * 64];   // 3 x 16 KB

    const int tid = threadIdx.x;
    int nt, mt;
    if (gridDim.y == 64) {                     // full dispatch (256 blocks)
        const int li = blockIdx.y * 4 + blockIdx.x;
        const int x  = li & 7;                 // XCD (round-robin assumption)
        const int j  = li >> 3;                // 0..31 within XCD
        mt = x * 8 + (j >> 2);                 // 8 m-panels per XCD
        nt = j & 3;
    } else {
        nt = blockIdx.x; mt = blockIdx.y;
    }
    const int lane = tid & 63;
    const int wv   = tid >> 6;                 // 0..7
    const int wr   = wv >> 1;                  // 0..3 (M)
    const int wc   = wv & 1;                   // 0..1 (N)
    const int lr   = lane & 15;
    const int lq   = lane >> 4;                // 0..3
    const int sb   = lr & 7;                   // read-side swizzle key

    const f32x4 z4 = {0.0f, 0.0f, 0.0f, 0.0f};
    f32x4 acc[4][4];
#pragma unroll
    for (int i = 0; i < 4; ++i)
#pragma unroll
        for (int j = 0; j < 4; ++j) acc[i][j] = z4;

    const int srow = tid >> 3;                          // 0..63
    const int gcb  = (tid & 7) ^ (srow & 7);            // pre-swizzled src blk
    const int scol = gcb * 8;

    const unsigned short* aptr[4];
    const unsigned short* bptr[2];
#pragma unroll
    for (int i = 0; i < 4; ++i) {
        int gr = mt * BM + i * 64 + srow;
        if (gr >= Mrows) gr = 0;
        aptr[i] = A + (size_t)gr * KPAD + scol;
    }
#pragma unroll
    for (int i = 0; i < 2; ++i)
        bptr[i] = Wb + (size_t)(nt * BN + i * 64 + srow) * KPAD + scol;

    const int kel0 = ((lq)     ^ sb) * 8;               // ks=0 swizzled col
    const int kel1 = ((4 + lq) ^ sb) * 8;               // ks=1 swizzled col
    const int aoff = (wr * 64 + lr) * 64;
    const int boff = (wc * 64 + lr) * 64;

#define STAGE_ALL(buf, koff)                                                \
    do {                                                                    \
        _Pragma("unroll")                                                   \
        for (int i_ = 0; i_ < 4; ++i_)                                      \
            GLDS16(aptr[i_] + (koff),                                       \
                   ((char*)As[buf]) + i_ * 8192 + tid * 16);                \
        _Pragma("unroll")                                                   \
        for (int i_ = 0; i_ < 2; ++i_)                                      \
            GLDS16(bptr[i_] + (koff),                                       \
                   ((char*)Bs[buf]) + i_ * 8192 + tid * 16);                \
    } while (0)

    // prologue: tiles 0 and 1 in flight; wait tile 0 (6 of tile 1 remain)
    STAGE_ALL(0, 0);
    STAGE_ALL(1, 64);
    asm volatile("s_waitcnt vmcnt(6)" ::: "memory");
    __builtin_amdgcn_sched_barrier(0);
    __builtin_amdgcn_s_barrier();
    __builtin_amdgcn_sched_barrier(0);

    // issue ph0 reads of tile 0
    bf16x8 afP[4], bfP[4], afN[4], bfN[4];
    {
        const unsigned short* as0 = &As[0][0];
        const unsigned short* bs0 = &Bs[0][0];
#pragma unroll
        for (int i = 0; i < 4; ++i)
            afP[i] = *(const bf16x8*)&as0[aoff + i * 1024 + kel0];
#pragma unroll
        for (int j = 0; j < 4; ++j)
            bfP[j] = *(const bf16x8*)&bs0[boff + j * 1024 + kel0];
    }
    __builtin_amdgcn_sched_barrier(0);

    int cur = 0, nxt = 1, nn = 2;
    for (int t = 0; t < NKT; ++t) {
        const unsigned short* as = &As[0][0] + cur * (BM * 64);
        const unsigned short* bs = &Bs[0][0] + cur * (BN * 64);

        // ---- issue ph1(t) reads (8) + 6 gloads for t+2 ----
#pragma unroll
        for (int i = 0; i < 4; ++i)
            afN[i] = *(const bf16x8*)&as[aoff + i * 1024 + kel1];
#pragma unroll
        for (int j = 0; j < 4; ++j)
            bfN[j] = *(const bf16x8*)&bs[boff + j * 1024 + kel1];
        if (t + 2 < NKT) STAGE_ALL(nn, (t + 2) * 64);
        __builtin_amdgcn_sched_barrier(0);

        // ---- ph0 MFMA (ph1 reads stream underneath) ----
        asm volatile("s_waitcnt lgkmcnt(8)" ::: "memory");
        __builtin_amdgcn_sched_barrier(0);
        __builtin_amdgcn_s_setprio(1);
#pragma unroll
        for (int i = 0; i < 4; ++i)
#pragma unroll
            for (int j = 0; j < 4; ++j)
                acc[i][j] = __builtin_amdgcn_mfma_f32_16x16x32_bf16(
                    afP[i], bfP[j], acc[i][j], 0, 0, 0);
        __builtin_amdgcn_s_setprio(0);
        __builtin_amdgcn_sched_barrier(0);

        // ---- all buf(t) reads done; cross into tile t+1's buffer ----
        asm volatile("s_waitcnt lgkmcnt(0)" ::: "memory");
        __builtin_amdgcn_sched_barrier(0);
        if (t + 1 < NKT) {
            if (t + 2 < NKT) {
                asm volatile("s_waitcnt vmcnt(6)" ::: "memory");
            } else {
                asm volatile("s_waitcnt vmcnt(0)" ::: "memory");
            }
            __builtin_amdgcn_sched_barrier(0);
            __builtin_amdgcn_s_barrier();
            __builtin_amdgcn_sched_barrier(0);
            // issue ph0 reads of tile t+1 (stream under ph1 MFMA below)
            const unsigned short* asn = &As[0][0] + nxt * (BM * 64);
            const unsigned short* bsn = &Bs[0][0] + nxt * (BN * 64);
#pragma unroll
            for (int i = 0; i < 4; ++i)
                afP[i] = *(const bf16x8*)&asn[aoff + i * 1024 + kel0];
#pragma unroll
            for (int j = 0; j < 4; ++j)
                bfP[j] = *(const bf16x8*)&bsn[boff + j * 1024 + kel0];
            __builtin_amdgcn_sched_barrier(0);
        }

        // ---- ph1 MFMA (tile t+1's ph0 reads stream underneath) ----
        __builtin_amdgcn_s_setprio(1);
#pragma unroll
        for (int i = 0; i < 4; ++i)
#pragma unroll
            for (int j = 0; j < 4; ++j)
                acc[i][j] = __builtin_amdgcn_mfma_f32_16x16x32_bf16(
                    afN[i], bfN[j], acc[i][j], 0, 0, 0);
        __builtin_amdgcn_s_setprio(0);
        __builtin_amdgcn_sched_barrier(0);

        const int tmp = cur; cur = nxt; nxt = nn; nn = tmp;
    }

    float bn[4];
#pragma unroll
    for (int j = 0; j < 4; ++j)
        bn[j] = bias[nt * BN + wc * 64 + j * 16 + lr];

#pragma unroll
    for (int i = 0; i < 4; ++i) {
        const int mbase = mt * BM + wr * 64 + i * 16 + lq * 4;
#pragma unroll
        for (int r = 0; r < 4; ++r) {
            const int m = mbase + r;
            if (m < Mrows) {
#pragma unroll
                for (int j = 0; j < 4; ++j) {
                    const int n = nt * BN + wc * 64 + j * 16 + lr;
                    out[(size_t)m * ODIM + n] = acc[i][j][r] + bn[j];
                }
            }
        }
    }
#undef STAGE_ALL
}

extern "C" void kernel_launch(void* const* d_in, const int* in_sizes, int n_in,
                              void* d_out, int out_size, void* d_ws, size_t ws_size,
                              hipStream_t stream) {
    const float* inp  = (const float*)d_in[0];
    const float* W    = (const float*)d_in[1];
    const float* bias = (const float*)d_in[2];
    float* out = (float*)d_out;

    const size_t wbBytes = (size_t)ODIM * KPAD * sizeof(unsigned short);
    const size_t sigPB   = (size_t)TSTEPS * KPAD * sizeof(unsigned short); // 2.42 MB
    const size_t ckptPB  = (size_t)15 * NSIG * sizeof(float);              // 0.28 MB
    const size_t perB    = sigPB + ckptPB;

    int nbMax = (int)((ws_size - wbBytes) / perB);
    if (nbMax > BATCH) nbMax = BATCH;
    if (nbMax < 1) nbMax = 1;

    unsigned short* sig  = (unsigned short*)d_ws;
    float*          ckpt = (float*)((char*)d_ws + (size_t)nbMax * sigPB);
    unsigned short* Wb   = (unsigned short*)((char*)d_ws + (ws_size - wbBytes));

    for (int b0 = 0; b0 < BATCH; b0 += nbMax) {
        const int nb = (b0 + nbMax <= BATCH) ? nbMax : (BATCH - b0);
        const int Mrows = nb * TSTEPS;
        const float* ipb = inp + (size_t)b0 * LSEQ * CIN;
        prep_kernel<<<4 * nb + WCVT_BLK, 512, 0, stream>>>(ipb, ckpt, W, Wb, nb);
        sig_write_kernel<<<dim3(NCHUNK, nb), 512, 0, stream>>>(ipb, ckpt, sig);
        gemm_kernel<<<dim3(ODIM / BN, (Mrows + BM - 1) / BM), 512, 0, stream>>>(
            sig, Wb, bias, out + (size_t)b0 * TSTEPS * ODIM, Mrows);
    }
}